// Round 1
// baseline (11548.122 us; speedup 1.0000x reference)
//
#include <hip/hip_runtime.h>
#include <hip/hip_bf16.h>

#define T_STEPS 128
#define DH      512
#define NPATCH  196
#define BATCH   16
#define VOCAB   10000

__device__ __forceinline__ float sigm(float x) { return 1.0f / (1.0f + __expf(-x)); }
// NaN-free fast tanh: 1 - 2/(e^{2x}+1); handles +-inf gracefully.
__device__ __forceinline__ float ftanh(float x) {
    float e = __expf(2.0f * x);
    return 1.0f - 2.0f / (e + 1.0f);
}

// C[M,N] = A[M,K] @ W[N,K]^T (+ bias). Row-major A (lda), W (ldw), C (ldc).
// BM=BN=64, BK=32, 256 threads, 4x4 micro-tile. M,K assumed multiples of 64/32; N edge-guarded.
__global__ __launch_bounds__(256)
void gemm_rt(const float* __restrict__ A, int lda,
             const float* __restrict__ W, int ldw,
             const float* __restrict__ bias,
             float* __restrict__ C, int ldc,
             int M, int N, int K)
{
    __shared__ float As[32][68];
    __shared__ float Ws[32][68];
    const int tid = threadIdx.x;
    const int tm = tid & 15, tn = tid >> 4;
    const int m0 = blockIdx.x * 64, n0 = blockIdx.y * 64;
    const int ar = tid >> 2, a4 = tid & 3;

    float acc[4][4];
#pragma unroll
    for (int i = 0; i < 4; ++i)
#pragma unroll
        for (int j = 0; j < 4; ++j) acc[i][j] = 0.0f;

    for (int k0 = 0; k0 < K; k0 += 32) {
        // stage A tile (64 rows x 32 k), transposed into As[k][m]
        {
            const float* src = A + (m0 + ar) * lda + k0;
            float4 v0 = *(const float4*)(src + a4 * 4);
            float4 v1 = *(const float4*)(src + 16 + a4 * 4);
            As[a4 * 4 + 0][ar] = v0.x; As[a4 * 4 + 1][ar] = v0.y;
            As[a4 * 4 + 2][ar] = v0.z; As[a4 * 4 + 3][ar] = v0.w;
            As[16 + a4 * 4 + 0][ar] = v1.x; As[16 + a4 * 4 + 1][ar] = v1.y;
            As[16 + a4 * 4 + 2][ar] = v1.z; As[16 + a4 * 4 + 3][ar] = v1.w;
        }
        // stage W tile (64 rows x 32 k), N edge-guarded
        {
            float4 v0 = {0, 0, 0, 0}, v1 = {0, 0, 0, 0};
            int nr = n0 + ar;
            if (nr < N) {
                const float* src = W + nr * ldw + k0;
                v0 = *(const float4*)(src + a4 * 4);
                v1 = *(const float4*)(src + 16 + a4 * 4);
            }
            Ws[a4 * 4 + 0][ar] = v0.x; Ws[a4 * 4 + 1][ar] = v0.y;
            Ws[a4 * 4 + 2][ar] = v0.z; Ws[a4 * 4 + 3][ar] = v0.w;
            Ws[16 + a4 * 4 + 0][ar] = v1.x; Ws[16 + a4 * 4 + 1][ar] = v1.y;
            Ws[16 + a4 * 4 + 2][ar] = v1.z; Ws[16 + a4 * 4 + 3][ar] = v1.w;
        }
        __syncthreads();
#pragma unroll
        for (int k = 0; k < 32; ++k) {
            float4 av = *(const float4*)&As[k][tm * 4];
            float4 wv = *(const float4*)&Ws[k][tn * 4];
            float a_[4] = {av.x, av.y, av.z, av.w};
            float w_[4] = {wv.x, wv.y, wv.z, wv.w};
#pragma unroll
            for (int i = 0; i < 4; ++i)
#pragma unroll
                for (int j = 0; j < 4; ++j) acc[i][j] += a_[i] * w_[j];
        }
        __syncthreads();
    }
#pragma unroll
    for (int i = 0; i < 4; ++i) {
        int m = m0 + tm * 4 + i;
#pragma unroll
        for (int j = 0; j < 4; ++j) {
            int n = n0 + tn * 4 + j;
            if (n < N) {
                float v = acc[i][j];
                if (bias) v += bias[n];
                C[m * ldc + n] = v;
            }
        }
    }
}

// h0 = cls@ih_w.T + ih_b ; c0 = cls@ic_w.T + ic_b   (16x512 each)
__global__ __launch_bounds__(256)
void h0c0_kernel(const float* __restrict__ cls,
                 const float* __restrict__ ihw, const float* __restrict__ ihb,
                 const float* __restrict__ icw, const float* __restrict__ icb,
                 float* __restrict__ h, float* __restrict__ c)
{
    int id = blockIdx.x * 256 + threadIdx.x;   // 0..16383
    int which = id >> 13;
    int b = (id >> 9) & 15;
    int d = id & 511;
    const float* w = (which ? icw : ihw) + d * 768;
    const float* x = cls + b * 768;
    float acc = which ? icb[d] : ihb[d];
    const float4* x4 = (const float4*)x;
    const float4* w4 = (const float4*)w;
#pragma unroll 4
    for (int k = 0; k < 192; ++k) {
        float4 a = x4[k], ww = w4[k];
        acc += a.x * ww.x + a.y * ww.y + a.z * ww.z + a.w * ww.w;
    }
    (which ? c : h)[b * 512 + d] = acc;
}

// x_all[b,t,:] = emb[tgt_ids[b,t], :]
__global__ __launch_bounds__(256)
void gather_kernel(const int* __restrict__ ids, const float* __restrict__ emb,
                   float* __restrict__ x_all)
{
    int q = blockIdx.x * 256 + threadIdx.x;    // 2048 rows * 128 float4
    if (q >= 2048 * 128) return;
    int r = q >> 7, k = q & 127;
    int tgt = ids[r];
    ((float4*)x_all)[r * 128 + k] = ((const float4*)emb)[tgt * 128 + k];
}

// Per step: [cell update + LN for step t-1] then attention -> ctx for step t.
// One block per batch element, 1024 threads.
__global__ __launch_bounds__(1024)
void attn_step(int t, const float* __restrict__ gates,
               float* __restrict__ h_cur, float* __restrict__ c_cur,
               float* __restrict__ h_all,
               const float* __restrict__ keys, const float* __restrict__ keysWk,
               const float* __restrict__ Wh, const float* __restrict__ vvec,
               const float* __restrict__ lng, const float* __restrict__ lnb,
               float* __restrict__ ctx)
{
    const int b = blockIdx.x, tid = threadIdx.x;
    __shared__ float hb[512], vv[512], ew[512], part[1024];
    __shared__ float sc[196], al[196], redA[20], redB[20];

    if (t > 0) {
        float hr = 0.0f;
        bool act = tid < 512;
        if (act) {
            int d = tid;
            const float* g = gates + b * 2048;
            float iv = g[d], fv = g[512 + d], gv = g[1024 + d], ov = g[1536 + d];
            float c = c_cur[b * 512 + d];
            float cn = sigm(fv) * c + sigm(iv) * ftanh(gv);
            c_cur[b * 512 + d] = cn;
            hr = sigm(ov) * ftanh(cn);
        }
        float v1 = hr, v2 = hr * hr;
#pragma unroll
        for (int m = 32; m; m >>= 1) { v1 += __shfl_xor(v1, m, 64); v2 += __shfl_xor(v2, m, 64); }
        if ((tid & 63) == 0) { redA[tid >> 6] = v1; redB[tid >> 6] = v2; }
        __syncthreads();
        if (tid == 0) {
            float s1 = 0, s2 = 0;
            for (int i = 0; i < 16; ++i) { s1 += redA[i]; s2 += redB[i]; }
            float mu = s1 * (1.0f / 512.0f);
            float var = s2 * (1.0f / 512.0f) - mu * mu;
            redA[16] = mu;
            redB[16] = rsqrtf(var + 1e-5f);
        }
        __syncthreads();
        if (act) {
            int d = tid;
            float hn = (hr - redA[16]) * redB[16] * lng[d] + lnb[d];
            h_cur[b * 512 + d] = hn;
            h_all[(b * T_STEPS + (t - 1)) * 512 + d] = hn;
            hb[d] = hn;
        }
    } else {
        if (tid < 512) hb[tid] = h_cur[b * 512 + tid];
    }
    if (tid < 512) vv[tid] = vvec[tid];
    __syncthreads();

    // hWh[d] = h . Wh[d,:]   (2 threads per d, 256-length halves)
    {
        int d = tid & 511, half = tid >> 9;
        const float4* hv = (const float4*)(hb) + half * 64;
        const float4* wr = (const float4*)(Wh + d * 512) + half * 64;
        float p = 0.0f;
#pragma unroll 8
        for (int i = 0; i < 64; ++i) {
            float4 a = hv[i], w = wr[i];
            p += a.x * w.x + a.y * w.y + a.z * w.z + a.w * w.w;
        }
        part[tid] = p;
    }
    __syncthreads();
    if (tid < 512) ew[tid] = part[tid] + part[tid + 512];
    __syncthreads();

    // scores[n] = sum_d tanh(ew[d] + keysWk[b,n,d]) * v[d]; one wave per n
    {
        int wid = tid >> 6, lane = tid & 63;
        for (int n = wid; n < NPATCH; n += 16) {
            const float* kw = keysWk + (b * NPATCH + n) * 512;
            float s = 0.0f;
#pragma unroll
            for (int i = 0; i < 8; ++i) {
                int d = lane + 64 * i;
                s += ftanh(ew[d] + kw[d]) * vv[d];
            }
#pragma unroll
            for (int m = 32; m; m >>= 1) s += __shfl_xor(s, m, 64);
            if (lane == 0) sc[n] = s;
        }
    }
    __syncthreads();
    // softmax over 196
    if (tid < 64) {
        float m = -1e30f;
        for (int i = tid; i < NPATCH; i += 64) m = fmaxf(m, sc[i]);
#pragma unroll
        for (int k = 32; k; k >>= 1) m = fmaxf(m, __shfl_xor(m, k, 64));
        if (tid == 0) redA[17] = m;
    }
    __syncthreads();
    if (tid < NPATCH) al[tid] = __expf(sc[tid] - redA[17]);
    __syncthreads();
    if (tid < 64) {
        float s = 0.0f;
        for (int i = tid; i < NPATCH; i += 64) s += al[i];
#pragma unroll
        for (int k = 32; k; k >>= 1) s += __shfl_xor(s, k, 64);
        if (tid == 0) redB[17] = s;
    }
    __syncthreads();
    // ctx[b,d] = (sum_n al[n]*keys[b,n,d]) / sum
    {
        int d = tid & 511, half = tid >> 9;
        const float* kb = keys + (b * NPATCH + half * 98) * 512 + d;
        float p = 0.0f;
#pragma unroll 4
        for (int n = 0; n < 98; ++n) p += al[half * 98 + n] * kb[n * 512];
        part[tid] = p;
        __syncthreads();
        if (tid < 512) ctx[b * 512 + tid] = (part[tid] + part[tid + 512]) * (1.0f / redB[17]);
    }
}

// gates[b,j] = bih[j]+bhh[j] + [x_t|ctx] . Wih[j,:] + h . Whh[j,:]
// grid (64 j-blocks x 2 b-groups), 256 threads; z,h staged in LDS (padded strides).
__global__ __launch_bounds__(256)
void gates_step(int t, const float* __restrict__ x_all, const float* __restrict__ ctx,
                const float* __restrict__ h_cur, const float* __restrict__ Wih,
                const float* __restrict__ Whh, const float* __restrict__ bih,
                const float* __restrict__ bhh, float* __restrict__ gates)
{
    __shared__ float zs[8][1032];
    __shared__ float hs[8][520];
    const int tid = threadIdx.x;
    const int jblk = blockIdx.x;    // 0..63
    const int bgrp = blockIdx.y;    // 0..1

    for (int q = tid; q < 8 * 256; q += 256) {
        int bb = q >> 8, k4 = q & 255;
        int b = bgrp * 8 + bb;
        float4 v;
        if (k4 < 128) v = ((const float4*)x_all)[(b * T_STEPS + t) * 128 + k4];
        else          v = ((const float4*)ctx)[b * 128 + (k4 - 128)];
        *(float4*)&zs[bb][k4 * 4] = v;
    }
    for (int q = tid; q < 8 * 128; q += 256) {
        int bb = q >> 7, k4 = q & 127;
        int b = bgrp * 8 + bb;
        *(float4*)&hs[bb][k4 * 4] = ((const float4*)h_cur)[b * 128 + k4];
    }
    __syncthreads();

    const int bb = tid & 7, jj = tid >> 3;   // jj 0..31
    const int j = jblk * 32 + jj;
    float acc = bih[j] + bhh[j];
    const float4* wz = (const float4*)(Wih + j * 1024);
    const float4* zz = (const float4*)&zs[bb][0];
#pragma unroll 8
    for (int k = 0; k < 256; ++k) {
        float4 a = zz[k], w = wz[k];
        acc += a.x * w.x + a.y * w.y + a.z * w.z + a.w * w.w;
    }
    const float4* wh = (const float4*)(Whh + j * 512);
    const float4* hh = (const float4*)&hs[bb][0];
#pragma unroll 8
    for (int k = 0; k < 128; ++k) {
        float4 a = hh[k], w = wh[k];
        acc += a.x * w.x + a.y * w.y + a.z * w.z + a.w * w.w;
    }
    int b = bgrp * 8 + bb;
    gates[b * 2048 + j] = acc;
}

// Cell + LN for the final step (t = 127) -> h_all[...,127,:]
__global__ __launch_bounds__(512)
void finish_kernel(const float* __restrict__ gates, float* __restrict__ c_cur,
                   const float* __restrict__ lng, const float* __restrict__ lnb,
                   float* __restrict__ h_all)
{
    int b = blockIdx.x, tid = threadIdx.x;  // 512 threads
    __shared__ float redA[10], redB[10];
    int d = tid;
    const float* g = gates + b * 2048;
    float iv = g[d], fv = g[512 + d], gv = g[1024 + d], ov = g[1536 + d];
    float c = c_cur[b * 512 + d];
    float cn = sigm(fv) * c + sigm(iv) * ftanh(gv);
    float hr = sigm(ov) * ftanh(cn);
    float v1 = hr, v2 = hr * hr;
#pragma unroll
    for (int m = 32; m; m >>= 1) { v1 += __shfl_xor(v1, m, 64); v2 += __shfl_xor(v2, m, 64); }
    if ((tid & 63) == 0) { redA[tid >> 6] = v1; redB[tid >> 6] = v2; }
    __syncthreads();
    if (tid == 0) {
        float s1 = 0, s2 = 0;
        for (int i = 0; i < 8; ++i) { s1 += redA[i]; s2 += redB[i]; }
        float mu = s1 * (1.0f / 512.0f);
        float var = s2 * (1.0f / 512.0f) - mu * mu;
        redA[8] = mu;
        redB[8] = rsqrtf(var + 1e-5f);
    }
    __syncthreads();
    float hn = (hr - redA[8]) * redB[8] * lng[d] + lnb[d];
    h_all[(b * T_STEPS + (T_STEPS - 1)) * 512 + d] = hn;
}

extern "C" void kernel_launch(void* const* d_in, const int* in_sizes, int n_in,
                              void* d_out, int out_size, void* d_ws, size_t ws_size,
                              hipStream_t stream)
{
    const float* patches = (const float*)d_in[0];
    const float* cls     = (const float*)d_in[1];
    const int*   tgt     = (const int*)d_in[2];
    const float* kv_w    = (const float*)d_in[3];
    const float* kv_b    = (const float*)d_in[4];
    const float* ih_w    = (const float*)d_in[5];
    const float* ih_b    = (const float*)d_in[6];
    const float* ic_w    = (const float*)d_in[7];
    const float* ic_b    = (const float*)d_in[8];
    const float* emb     = (const float*)d_in[9];
    const float* Wh      = (const float*)d_in[10];
    const float* Wk      = (const float*)d_in[11];
    const float* av      = (const float*)d_in[12];
    const float* Wih     = (const float*)d_in[13];
    const float* Whh     = (const float*)d_in[14];
    const float* bih     = (const float*)d_in[15];
    const float* bhh     = (const float*)d_in[16];
    const float* lng     = (const float*)d_in[17];
    const float* lnb     = (const float*)d_in[18];
    const float* outw    = (const float*)d_in[19];
    const float* outb    = (const float*)d_in[20];
    float* out = (float*)d_out;

    char* ws = (char*)d_ws;
    float* keys   = (float*)ws; ws += (size_t)BATCH * NPATCH * 512 * 4;  // 6.42 MB
    float* keysWk = (float*)ws; ws += (size_t)BATCH * NPATCH * 512 * 4;  // 6.42 MB
    float* x_all  = (float*)ws; ws += (size_t)BATCH * T_STEPS * 512 * 4; // 4 MB
    float* h_all  = (float*)ws; ws += (size_t)BATCH * T_STEPS * 512 * 4; // 4 MB
    float* ctx    = (float*)ws; ws += (size_t)BATCH * 512 * 4;
    float* h_cur  = (float*)ws; ws += (size_t)BATCH * 512 * 4;
    float* c_cur  = (float*)ws; ws += (size_t)BATCH * 512 * 4;
    float* gates  = (float*)ws; ws += (size_t)BATCH * 2048 * 4;

    // keys = patches @ kv_w.T + kv_b   (3136 x 512, K=768)
    dim3 g1(3136 / 64, 512 / 64);
    gemm_rt<<<g1, 256, 0, stream>>>(patches, 768, kv_w, 768, kv_b, keys, 512, 3136, 512, 768);
    // keysWk = keys @ Wk.T             (3136 x 512, K=512)
    gemm_rt<<<g1, 256, 0, stream>>>(keys, 512, Wk, 512, nullptr, keysWk, 512, 3136, 512, 512);
    // h0, c0
    h0c0_kernel<<<64, 256, 0, stream>>>(cls, ih_w, ih_b, ic_w, ic_b, h_cur, c_cur);
    // x_all gather
    gather_kernel<<<1024, 256, 0, stream>>>(tgt, emb, x_all);

    for (int t = 0; t < T_STEPS; ++t) {
        attn_step<<<BATCH, 1024, 0, stream>>>(t, gates, h_cur, c_cur, h_all,
                                              keys, keysWk, Wh, av, lng, lnb, ctx);
        gates_step<<<dim3(64, 2), 256, 0, stream>>>(t, x_all, ctx, h_cur,
                                                    Wih, Whh, bih, bhh, gates);
    }
    finish_kernel<<<BATCH, 512, 0, stream>>>(gates, c_cur, lng, lnb, h_all);

    // logits = h_all @ out_w.T + out_b   (2048 x 10000, K=512)
    dim3 g2(2048 / 64, (VOCAB + 63) / 64);
    gemm_rt<<<g2, 256, 0, stream>>>(h_all, 512, outw, 512, outb, out, VOCAB, 2048, VOCAB, 512);
}

// Round 4
// 10705.222 us; speedup vs baseline: 1.0787x; 1.0787x over previous
//
#include <hip/hip_runtime.h>
#include <hip/hip_bf16.h>

#define T_STEPS 128
#define DH      512
#define NPATCH  196
#define BATCH   16
#define VOCAB   10000

typedef __attribute__((ext_vector_type(8))) short bf16x8;
typedef __attribute__((ext_vector_type(4))) float f32x4;

__device__ __forceinline__ float sigm(float x) { return 1.0f / (1.0f + __expf(-x)); }
__device__ __forceinline__ float ftanh(float x) {
    float e = __expf(2.0f * x);
    return 1.0f - 2.0f / (e + 1.0f);
}
// fp32 -> bf16 round-to-nearest-even
__device__ __forceinline__ unsigned short f2b(float x) {
    union { float f; unsigned u; } v; v.f = x;
    unsigned r = (v.u + 0x7FFFu + ((v.u >> 16) & 1u)) >> 16;
    return (unsigned short)r;
}
__device__ __forceinline__ float b2f(unsigned short h) {
    union { unsigned u; float f; } v; v.u = ((unsigned)h) << 16;
    return v.f;
}

// fp32 -> single bf16 (n multiple of 8)
__global__ __launch_bounds__(256)
void cvt_kernel(const float* __restrict__ src, unsigned short* __restrict__ dst, int n)
{
    int i = (blockIdx.x * 256 + threadIdx.x) * 8;
    if (i >= n) return;
    float4 v0 = *(const float4*)(src + i);
    float4 v1 = *(const float4*)(src + i + 4);
    float xs[8] = {v0.x, v0.y, v0.z, v0.w, v1.x, v1.y, v1.z, v1.w};
    bf16x8 o;
#pragma unroll
    for (int j = 0; j < 8; ++j) o[j] = (short)f2b(xs[j]);
    *(bf16x8*)(dst + i) = o;
}

// fp32 -> split bf16 hi+lo: b2f(hi)+b2f(lo) ~ x to ~2^-17 rel
__global__ __launch_bounds__(256)
void cvt_split_kernel(const float* __restrict__ src, unsigned short* __restrict__ hi,
                      unsigned short* __restrict__ lo, int n)
{
    int i = (blockIdx.x * 256 + threadIdx.x) * 8;
    if (i >= n) return;
    float4 v0 = *(const float4*)(src + i);
    float4 v1 = *(const float4*)(src + i + 4);
    float xs[8] = {v0.x, v0.y, v0.z, v0.w, v1.x, v1.y, v1.z, v1.w};
    bf16x8 h_, l_;
#pragma unroll
    for (int j = 0; j < 8; ++j) {
        unsigned short hb = f2b(xs[j]);
        float r = xs[j] - b2f(hb);
        h_[j] = (short)hb;
        l_[j] = (short)f2b(r);
    }
    *(bf16x8*)(hi + i) = h_;
    *(bf16x8*)(lo + i) = l_;
}

// C[M,N] = (AH+AL)[M,K] @ (WH+WL)[N,K]^T + bias, 3-term split (AL,WL nullable).
// Outputs: fp32 C and/or split bf16 CbH/CbL (all nullable).
// BM=BN=128, 4 waves (2x2), each wave 64x64 via 4x4 frags of 16x16x32 MFMA.
__global__ __launch_bounds__(256)
void gemm_mfma(const unsigned short* __restrict__ AH, const unsigned short* __restrict__ AL,
               const unsigned short* __restrict__ WH, const unsigned short* __restrict__ WL,
               const float* __restrict__ bias, float* __restrict__ C,
               unsigned short* __restrict__ CbH, unsigned short* __restrict__ CbL,
               int M, int N, int K)
{
    const int tid = threadIdx.x, wid = tid >> 6, l = tid & 63;
    const int m0 = blockIdx.x * 128 + (wid >> 1) * 64;
    const int n0 = blockIdx.y * 128 + (wid & 1) * 64;
    const int lm = l & 15, lk = (l >> 4) * 8;
    f32x4 acc[4][4];
#pragma unroll
    for (int i = 0; i < 4; ++i)
#pragma unroll
        for (int j = 0; j < 4; ++j) acc[i][j] = (f32x4){0.f, 0.f, 0.f, 0.f};
    const bf16x8 az = {0,0,0,0,0,0,0,0};

    for (int k0 = 0; k0 < K; k0 += 32) {
        bf16x8 aH[4], aL[4];
#pragma unroll
        for (int mi = 0; mi < 4; ++mi) {
            int m = m0 + mi * 16 + lm;
            aH[mi] = (m < M) ? *(const bf16x8*)(AH + (size_t)m * K + k0 + lk) : az;
            aL[mi] = (AL && m < M) ? *(const bf16x8*)(AL + (size_t)m * K + k0 + lk) : az;
        }
#pragma unroll
        for (int ni = 0; ni < 4; ++ni) {
            int n = n0 + ni * 16 + lm;
            bf16x8 bH = az, bL = az;
            if (n < N) {
                bH = *(const bf16x8*)(WH + (size_t)n * K + k0 + lk);
                if (WL) bL = *(const bf16x8*)(WL + (size_t)n * K + k0 + lk);
            }
#pragma unroll
            for (int mi = 0; mi < 4; ++mi) {
                acc[mi][ni] = __builtin_amdgcn_mfma_f32_16x16x32_bf16(aH[mi], bH, acc[mi][ni], 0, 0, 0);
                if (WL) acc[mi][ni] = __builtin_amdgcn_mfma_f32_16x16x32_bf16(aH[mi], bL, acc[mi][ni], 0, 0, 0);
                if (AL) acc[mi][ni] = __builtin_amdgcn_mfma_f32_16x16x32_bf16(aL[mi], bH, acc[mi][ni], 0, 0, 0);
            }
        }
    }
    const int rr = (l >> 4) * 4;
#pragma unroll
    for (int mi = 0; mi < 4; ++mi) {
        int mb = m0 + mi * 16 + rr;
#pragma unroll
        for (int ni = 0; ni < 4; ++ni) {
            int n = n0 + ni * 16 + lm;
            if (n < N) {
                float bs = bias ? bias[n] : 0.f;
#pragma unroll
                for (int r = 0; r < 4; ++r) {
                    int mm = mb + r;
                    if (mm < M) {
                        float v = acc[mi][ni][r] + bs;
                        if (C)   C[(size_t)mm * N + n] = v;
                        if (CbH) {
                            unsigned short hb = f2b(v);
                            CbH[(size_t)mm * N + n] = hb;
                            if (CbL) CbL[(size_t)mm * N + n] = f2b(v - b2f(hb));
                        }
                    }
                }
            }
        }
    }
}

// h0 (fp32 h_raw + split h_cur) and c0 (fp32)
__global__ __launch_bounds__(256)
void h0c0_kernel(const float* __restrict__ cls,
                 const float* __restrict__ ihw, const float* __restrict__ ihb,
                 const float* __restrict__ icw, const float* __restrict__ icb,
                 float* __restrict__ c_cur, float* __restrict__ h_raw,
                 unsigned short* __restrict__ h_curH, unsigned short* __restrict__ h_curL)
{
    int id = blockIdx.x * 256 + threadIdx.x;   // 0..16383
    int which = id >> 13;
    int b = (id >> 9) & 15;
    int d = id & 511;
    const float* w = (which ? icw : ihw) + d * 768;
    const float* x = cls + b * 768;
    float acc = which ? icb[d] : ihb[d];
    const float4* x4 = (const float4*)x;
    const float4* w4 = (const float4*)w;
#pragma unroll 4
    for (int k = 0; k < 192; ++k) {
        float4 a = x4[k], ww = w4[k];
        acc += a.x * ww.x + a.y * ww.y + a.z * ww.z + a.w * ww.w;
    }
    if (which) c_cur[b * 512 + d] = acc;
    else {
        h_raw[b * 512 + d] = acc;
        unsigned short hb = f2b(acc);
        h_curH[b * 512 + d] = hb;
        h_curL[b * 512 + d] = f2b(acc - b2f(hb));
    }
}

// x split: xH/xL[b,t,:] = split(emb[tgt_ids[b,t], :])
__global__ __launch_bounds__(256)
void gather_kernel(const int* __restrict__ ids, const float* __restrict__ emb,
                   unsigned short* __restrict__ xH, unsigned short* __restrict__ xL)
{
    int q = blockIdx.x * 256 + threadIdx.x;    // 2048 rows * 64 chunks of 8
    if (q >= 2048 * 64) return;
    int r = q >> 6, c = (q & 63) * 8;
    int tgt = ids[r];
    const float4* s = (const float4*)(emb + (size_t)tgt * 512 + c);
    float4 v0 = s[0], v1 = s[1];
    float xs[8] = {v0.x, v0.y, v0.z, v0.w, v1.x, v1.y, v1.z, v1.w};
    bf16x8 oh, ol;
#pragma unroll
    for (int j = 0; j < 8; ++j) {
        unsigned short hb = f2b(xs[j]);
        oh[j] = (short)hb;
        ol[j] = (short)f2b(xs[j] - b2f(hb));
    }
    *(bf16x8*)(xH + (size_t)r * 512 + c) = oh;
    *(bf16x8*)(xL + (size_t)r * 512 + c) = ol;
}

// Per batch: finalize h_{t-1} (LN, split write), ew = h@Wh^T (split W, fp32 h),
// scores (fp32 keysWk), softmax, ctx (fp32 keys).
__global__ __launch_bounds__(1024)
void attn_kernel(int t, const float* __restrict__ partials, const float* __restrict__ h_raw,
                 const float* __restrict__ lng, const float* __restrict__ lnb,
                 unsigned short* __restrict__ h_curH, unsigned short* __restrict__ h_curL,
                 unsigned short* __restrict__ h_all_b,
                 const unsigned short* __restrict__ WhH, const unsigned short* __restrict__ WhL,
                 const float* __restrict__ keysWk_f, const float* __restrict__ keys_f,
                 const float* __restrict__ vvec, float* __restrict__ ctx)
{
    const int b = blockIdx.x, tid = threadIdx.x;
    __shared__ float hn[512], ew[512], vv[512];
    __shared__ float pbuf[4][512];
    __shared__ float sc[200], al[200], mred[4];

    if (t > 0) {
        if (tid < 16) {
            float v1 = partials[(tid * 16 + b) * 2 + 0];
            float v2 = partials[(tid * 16 + b) * 2 + 1];
#pragma unroll
            for (int m = 8; m; m >>= 1) { v1 += __shfl_xor(v1, m, 16); v2 += __shfl_xor(v2, m, 16); }
            if (tid == 0) {
                float mu = v1 * (1.f / 512.f);
                float var = v2 * (1.f / 512.f) - mu * mu;
                mred[0] = mu; mred[1] = rsqrtf(var + 1e-5f);
            }
        }
        __syncthreads();
        if (tid < 512) {
            float hv = (h_raw[b * 512 + tid] - mred[0]) * mred[1] * lng[tid] + lnb[tid];
            hn[tid] = hv;
            unsigned short hb_ = f2b(hv);
            h_curH[b * 512 + tid] = hb_;
            h_curL[b * 512 + tid] = f2b(hv - b2f(hb_));
            h_all_b[((size_t)b * T_STEPS + (t - 1)) * 512 + tid] = hb_;
        }
    } else {
        if (tid < 512) hn[tid] = h_raw[b * 512 + tid];
    }
    if (tid < 512) vv[tid] = vvec[tid];
    __syncthreads();

    // ew[e] = hn . (WhH[e,:]+WhL[e,:])  — 2 threads/e, 256-length halves
    {
        int e = tid & 511, half = tid >> 9;
        const bf16x8* wh = (const bf16x8*)(WhH + (size_t)e * 512) + half * 32;
        const bf16x8* wl = (const bf16x8*)(WhL + (size_t)e * 512) + half * 32;
        const float* hh = hn + half * 256;
        float s = 0.f;
        for (int q = 0; q < 32; ++q) {
            bf16x8 a = wh[q], c = wl[q];
#pragma unroll
            for (int j = 0; j < 8; ++j)
                s += (b2f((unsigned short)a[j]) + b2f((unsigned short)c[j])) * hh[q * 8 + j];
        }
        pbuf[half][e] = s;
    }
    __syncthreads();
    if (tid < 512) ew[tid] = pbuf[0][tid] + pbuf[1][tid];
    __syncthreads();

    // scores[n] = sum_d tanh(ew[d]+keysWk[b,n,d]) * v[d]; one wave per n
    {
        int wid = tid >> 6, lane = tid & 63;
        for (int n = wid; n < NPATCH; n += 16) {
            const float* kwp = keysWk_f + ((size_t)(b * NPATCH + n)) * 512 + lane * 8;
            float4 k0 = ((const float4*)kwp)[0], k1 = ((const float4*)kwp)[1];
            float kv[8] = {k0.x, k0.y, k0.z, k0.w, k1.x, k1.y, k1.z, k1.w};
            float s = 0.f;
#pragma unroll
            for (int j = 0; j < 8; ++j) {
                int d = lane * 8 + j;
                s += ftanh(ew[d] + kv[j]) * vv[d];
            }
#pragma unroll
            for (int m = 32; m; m >>= 1) s += __shfl_xor(s, m, 64);
            if (lane == 0) sc[n] = s;
        }
    }
    __syncthreads();
    if (tid < 64) {
        float m = -1e30f;
        for (int i = tid; i < NPATCH; i += 64) m = fmaxf(m, sc[i]);
#pragma unroll
        for (int k = 32; k; k >>= 1) m = fmaxf(m, __shfl_xor(m, k, 64));
        if (tid == 0) mred[2] = m;
    }
    __syncthreads();
    if (tid < NPATCH) al[tid] = __expf(sc[tid] - mred[2]);
    __syncthreads();
    if (tid < 64) {
        float s = 0.f;
        for (int i = tid; i < NPATCH; i += 64) s += al[i];
#pragma unroll
        for (int k = 32; k; k >>= 1) s += __shfl_xor(s, k, 64);
        if (tid == 0) mred[3] = 1.f / s;
    }
    __syncthreads();
    // ctx[b,d] = sum_n al[n]*keys[b,n,d] * (1/sum)
    {
        int q = tid >> 8, d2 = tid & 255;
        float p0 = 0.f, p1 = 0.f;
        const float* kb = keys_f + (size_t)(b * NPATCH) * 512 + d2 * 2;
        for (int n = q * 49; n < q * 49 + 49; ++n) {
            float2 u = *(const float2*)(kb + (size_t)n * 512);
            p0 += al[n] * u.x;
            p1 += al[n] * u.y;
        }
        pbuf[q][d2 * 2] = p0; pbuf[q][d2 * 2 + 1] = p1;
    }
    __syncthreads();
    if (tid < 512)
        ctx[b * 512 + tid] = (pbuf[0][tid] + pbuf[1][tid] + pbuf[2][tid] + pbuf[3][tid]) * mred[3];
}

// grid (16 d-blocks x 2 b-groups), 256 thr (4 waves = 4 gate types), 8 batches/block.
// gates = (zH+zL)@(WihH+WihL)^T + (hH+hL)@(WhhH+WhhL)^T + biases  (3-term split MFMA);
// then cell: c, h_raw, LN partials. MFMA A rows 8..15 are duplicates (unwritten).
__global__ __launch_bounds__(256)
void gates_kernel(int t, const unsigned short* __restrict__ xH, const unsigned short* __restrict__ xL,
                  const float* __restrict__ ctx,
                  const unsigned short* __restrict__ hH, const unsigned short* __restrict__ hL,
                  const unsigned short* __restrict__ WihH, const unsigned short* __restrict__ WihL,
                  const unsigned short* __restrict__ WhhH, const unsigned short* __restrict__ WhhL,
                  const float* __restrict__ bih, const float* __restrict__ bhh,
                  float* __restrict__ c_cur, float* __restrict__ h_raw,
                  float* __restrict__ partials)
{
    __shared__ unsigned short zsH[8][1032], zsL[8][1032];
    __shared__ unsigned short hsH[8][520], hsL[8][520];
    __shared__ float gl[8][132];
    __shared__ float bias_l[128];
    const int tid = threadIdx.x, blk = blockIdx.x, bgrp = blockIdx.y;
    {
        int bb = tid >> 5, seg = tid & 31;
        int b = bgrp * 8 + bb;
        if (seg < 16) {                 // x part: 32 bf16 at c = seg*32
            int c = seg * 32;
            const bf16x8* sH = (const bf16x8*)(xH + ((size_t)(b * T_STEPS + t)) * 512 + c);
            const bf16x8* sL = (const bf16x8*)(xL + ((size_t)(b * T_STEPS + t)) * 512 + c);
            bf16x8* dH = (bf16x8*)&zsH[bb][c];
            bf16x8* dL = (bf16x8*)&zsL[bb][c];
#pragma unroll
            for (int q = 0; q < 4; ++q) { dH[q] = sH[q]; dL[q] = sL[q]; }
        } else {                        // ctx part: 32 fp32 split at 512 + cc
            int cc = (seg - 16) * 32;
            const float4* cs = (const float4*)(ctx + b * 512 + cc);
#pragma unroll
            for (int q = 0; q < 8; ++q) {
                float4 v = cs[q];
                float xs[4] = {v.x, v.y, v.z, v.w};
#pragma unroll
                for (int i = 0; i < 4; ++i) {
                    unsigned short hb = f2b(xs[i]);
                    zsH[bb][512 + cc + q * 4 + i] = hb;
                    zsL[bb][512 + cc + q * 4 + i] = f2b(xs[i] - b2f(hb));
                }
            }
        }
        // h: 16 bf16 per seg
        int ch = seg * 16;
        const bf16x8* shH = (const bf16x8*)(hH + b * 512 + ch);
        const bf16x8* shL = (const bf16x8*)(hL + b * 512 + ch);
        bf16x8* dhH = (bf16x8*)&hsH[bb][ch];
        bf16x8* dhL = (bf16x8*)&hsL[bb][ch];
#pragma unroll
        for (int q = 0; q < 2; ++q) { dhH[q] = shH[q]; dhL[q] = shL[q]; }
    }
    if (tid < 128) {
        int j = (tid >> 5) * 512 + blk * 32 + (tid & 31);
        bias_l[tid] = bih[j] + bhh[j];
    }
    __syncthreads();

    const int wid = tid >> 6, l = tid & 63, lb = l & 15, lk = (l >> 4) * 8, bbl = lb & 7;
    f32x4 acc0 = {0.f,0.f,0.f,0.f}, acc1 = {0.f,0.f,0.f,0.f};
    const int j0 = wid * 512 + blk * 32;
    {
        const unsigned short* W0H = WihH + (size_t)(j0 + lb) * 1024;
        const unsigned short* W0L = WihL + (size_t)(j0 + lb) * 1024;
        const unsigned short* W1H = WihH + (size_t)(j0 + 16 + lb) * 1024;
        const unsigned short* W1L = WihL + (size_t)(j0 + 16 + lb) * 1024;
        for (int k0 = 0; k0 < 1024; k0 += 32) {
            bf16x8 aH = *(const bf16x8*)&zsH[bbl][k0 + lk];
            bf16x8 aL = *(const bf16x8*)&zsL[bbl][k0 + lk];
            bf16x8 b0H = *(const bf16x8*)(W0H + k0 + lk);
            bf16x8 b0L = *(const bf16x8*)(W0L + k0 + lk);
            bf16x8 b1H = *(const bf16x8*)(W1H + k0 + lk);
            bf16x8 b1L = *(const bf16x8*)(W1L + k0 + lk);
            acc0 = __builtin_amdgcn_mfma_f32_16x16x32_bf16(aH, b0H, acc0, 0, 0, 0);
            acc0 = __builtin_amdgcn_mfma_f32_16x16x32_bf16(aH, b0L, acc0, 0, 0, 0);
            acc0 = __builtin_amdgcn_mfma_f32_16x16x32_bf16(aL, b0H, acc0, 0, 0, 0);
            acc1 = __builtin_amdgcn_mfma_f32_16x16x32_bf16(aH, b1H, acc1, 0, 0, 0);
            acc1 = __builtin_amdgcn_mfma_f32_16x16x32_bf16(aH, b1L, acc1, 0, 0, 0);
            acc1 = __builtin_amdgcn_mfma_f32_16x16x32_bf16(aL, b1H, acc1, 0, 0, 0);
        }
        const unsigned short* V0H = WhhH + (size_t)(j0 + lb) * 512;
        const unsigned short* V0L = WhhL + (size_t)(j0 + lb) * 512;
        const unsigned short* V1H = WhhH + (size_t)(j0 + 16 + lb) * 512;
        const unsigned short* V1L = WhhL + (size_t)(j0 + 16 + lb) * 512;
        for (int k0 = 0; k0 < 512; k0 += 32) {
            bf16x8 aH = *(const bf16x8*)&hsH[bbl][k0 + lk];
            bf16x8 aL = *(const bf16x8*)&hsL[bbl][k0 + lk];
            bf16x8 b0H = *(const bf16x8*)(V0H + k0 + lk);
            bf16x8 b0L = *(const bf16x8*)(V0L + k0 + lk);
            bf16x8 b1H = *(const bf16x8*)(V1H + k0 + lk);
            bf16x8 b1L = *(const bf16x8*)(V1L + k0 + lk);
            acc0 = __builtin_amdgcn_mfma_f32_16x16x32_bf16(aH, b0H, acc0, 0, 0, 0);
            acc0 = __builtin_amdgcn_mfma_f32_16x16x32_bf16(aH, b0L, acc0, 0, 0, 0);
            acc0 = __builtin_amdgcn_mfma_f32_16x16x32_bf16(aL, b0H, acc0, 0, 0, 0);
            acc1 = __builtin_amdgcn_mfma_f32_16x16x32_bf16(aH, b1H, acc1, 0, 0, 0);
            acc1 = __builtin_amdgcn_mfma_f32_16x16x32_bf16(aH, b1L, acc1, 0, 0, 0);
            acc1 = __builtin_amdgcn_mfma_f32_16x16x32_bf16(aL, b1H, acc1, 0, 0, 0);
        }
    }
    {
        int brow = (l >> 4) * 4, jj0 = wid * 32 + lb;
#pragma unroll
        for (int r = 0; r < 4; ++r) {
            if (brow + r < 8) {
                gl[brow + r][jj0]      = acc0[r] + bias_l[jj0];
                gl[brow + r][jj0 + 16] = acc1[r] + bias_l[jj0 + 16];
            }
        }
    }
    __syncthreads();
    {
        int b8 = tid >> 5, dl = tid & 31;
        int b = bgrp * 8 + b8, dg = blk * 32 + dl;
        float iv = gl[b8][dl], fv = gl[b8][32 + dl], gv = gl[b8][64 + dl], ov = gl[b8][96 + dl];
        float c = c_cur[b * 512 + dg];
        float cn = sigm(fv) * c + sigm(iv) * ftanh(gv);
        c_cur[b * 512 + dg] = cn;
        float hr = sigm(ov) * ftanh(cn);
        h_raw[b * 512 + dg] = hr;
        float s1 = hr, s2 = hr * hr;
#pragma unroll
        for (int m = 16; m; m >>= 1) { s1 += __shfl_xor(s1, m, 32); s2 += __shfl_xor(s2, m, 32); }
        if (dl == 0) {
            partials[(blk * 16 + b) * 2 + 0] = s1;
            partials[(blk * 16 + b) * 2 + 1] = s2;
        }
    }
}

// final step's h (t = 127) -> h_all_b row 127
__global__ __launch_bounds__(512)
void finish_kernel(const float* __restrict__ partials, const float* __restrict__ h_raw,
                   const float* __restrict__ lng, const float* __restrict__ lnb,
                   unsigned short* __restrict__ h_all_b)
{
    int b = blockIdx.x, tid = threadIdx.x;
    __shared__ float mred[2];
    if (tid < 16) {
        float v1 = partials[(tid * 16 + b) * 2 + 0];
        float v2 = partials[(tid * 16 + b) * 2 + 1];
#pragma unroll
        for (int m = 8; m; m >>= 1) { v1 += __shfl_xor(v1, m, 16); v2 += __shfl_xor(v2, m, 16); }
        if (tid == 0) {
            float mu = v1 * (1.f / 512.f);
            float var = v2 * (1.f / 512.f) - mu * mu;
            mred[0] = mu; mred[1] = rsqrtf(var + 1e-5f);
        }
    }
    __syncthreads();
    float hn = (h_raw[b * 512 + tid] - mred[0]) * mred[1] * lng[tid] + lnb[tid];
    h_all_b[((size_t)b * T_STEPS + (T_STEPS - 1)) * 512 + tid] = f2b(hn);
}

extern "C" void kernel_launch(void* const* d_in, const int* in_sizes, int n_in,
                              void* d_out, int out_size, void* d_ws, size_t ws_size,
                              hipStream_t stream)
{
    const float* patches = (const float*)d_in[0];
    const float* cls     = (const float*)d_in[1];
    const int*   tgt     = (const int*)d_in[2];
    const float* kv_w    = (const float*)d_in[3];
    const float* kv_b    = (const float*)d_in[4];
    const float* ih_w    = (const float*)d_in[5];
    const float* ih_b    = (const float*)d_in[6];
    const float* ic_w    = (const float*)d_in[7];
    const float* ic_b    = (const float*)d_in[8];
    const float* emb     = (const float*)d_in[9];
    const float* Wh      = (const float*)d_in[10];
    const float* Wk      = (const float*)d_in[11];
    const float* av      = (const float*)d_in[12];
    const float* Wih     = (const float*)d_in[13];
    const float* Whh     = (const float*)d_in[14];
    const float* bih     = (const float*)d_in[15];
    const float* bhh     = (const float*)d_in[16];
    const float* lng     = (const float*)d_in[17];
    const float* lnb     = (const float*)d_in[18];
    const float* outw    = (const float*)d_in[19];
    const float* outb    = (const float*)d_in[20];
    float* out = (float*)d_out;

    char* wsp = (char*)d_ws;
    auto carve = [&](size_t bytes) -> char* {
        char* p = wsp; wsp += (bytes + 255) & ~(size_t)255; return p;
    };
    float*          keys_f   = (float*)carve((size_t)3136 * 512 * 4);            // 6.4 MB
    float*          keysWk_f = (float*)carve((size_t)3136 * 512 * 4);            // 6.4 MB
    unsigned short* keysH    = (unsigned short*)carve((size_t)3136 * 512 * 2);   // 3.2 MB
    unsigned short* keysL    = (unsigned short*)carve((size_t)3136 * 512 * 2);   // 3.2 MB
    unsigned short* xH       = (unsigned short*)carve((size_t)2048 * 512 * 2);   // 2 MB
    unsigned short* xL       = (unsigned short*)carve((size_t)2048 * 512 * 2);   // 2 MB
    unsigned short* h_all_b  = (unsigned short*)carve((size_t)2048 * 512 * 2);   // 2 MB
    unsigned short* wihH     = (unsigned short*)carve((size_t)2048 * 1024 * 2);  // 4 MB
    unsigned short* wihL     = (unsigned short*)carve((size_t)2048 * 1024 * 2);  // 4 MB
    unsigned short* whhH     = (unsigned short*)carve((size_t)2048 * 512 * 2);   // 2 MB
    unsigned short* whhL     = (unsigned short*)carve((size_t)2048 * 512 * 2);   // 2 MB
    unsigned short* whH      = (unsigned short*)carve((size_t)512 * 512 * 2);
    unsigned short* whL      = (unsigned short*)carve((size_t)512 * 512 * 2);
    unsigned short* kvwH     = (unsigned short*)carve((size_t)512 * 768 * 2);
    unsigned short* kvwL     = (unsigned short*)carve((size_t)512 * 768 * 2);
    unsigned short* wkH      = (unsigned short*)carve((size_t)512 * 512 * 2);
    unsigned short* wkL      = (unsigned short*)carve((size_t)512 * 512 * 2);
    unsigned short* outw_b   = (unsigned short*)carve((size_t)VOCAB * 512 * 2);  // 10.2 MB
    float* ctx      = (float*)carve((size_t)16 * 512 * 4);
    float* c_cur    = (float*)carve((size_t)16 * 512 * 4);
    float* h_raw    = (float*)carve((size_t)16 * 512 * 4);
    unsigned short* h_curH = (unsigned short*)carve((size_t)16 * 512 * 2);
    unsigned short* h_curL = (unsigned short*)carve((size_t)16 * 512 * 2);
    float* partials = (float*)carve((size_t)16 * 16 * 2 * 4);
    // patches split (4.82+4.82 MB) aliases outw_b's 10.24 MB; outw converted after keys GEMM.
    unsigned short* patH = outw_b;
    unsigned short* patL = outw_b + (size_t)3136 * 768;

    auto cvt = [&](const float* s, unsigned short* d, int n) {
        cvt_kernel<<<(n / 8 + 255) / 256, 256, 0, stream>>>(s, d, n);
    };
    auto cvts = [&](const float* s, unsigned short* dh, unsigned short* dl, int n) {
        cvt_split_kernel<<<(n / 8 + 255) / 256, 256, 0, stream>>>(s, dh, dl, n);
    };
    cvts(patches, patH, patL, 3136 * 768);
    cvts(kv_w, kvwH, kvwL, 512 * 768);
    cvts(Wk, wkH, wkL, 512 * 512);
    cvts(Wh, whH, whL, 512 * 512);
    cvts(Wih, wihH, wihL, 2048 * 1024);
    cvts(Whh, whhH, whhL, 2048 * 512);

    // keys = patches @ kv_w^T + kv_b : fp32 + split bf16 outputs
    gemm_mfma<<<dim3(25, 4), 256, 0, stream>>>(patH, patL, kvwH, kvwL, kv_b,
                                               keys_f, keysH, keysL, 3136, 512, 768);
    // patches region free now: convert outw into it (stream-ordered after GEMM1)
    cvt(outw, outw_b, VOCAB * 512);
    // keysWk = keys @ Wk^T : fp32 out
    gemm_mfma<<<dim3(25, 4), 256, 0, stream>>>(keysH, keysL, wkH, wkL, nullptr,
                                               keysWk_f, nullptr, nullptr, 3136, 512, 512);

    h0c0_kernel<<<64, 256, 0, stream>>>(cls, ih_w, ih_b, ic_w, ic_b, c_cur, h_raw, h_curH, h_curL);
    gather_kernel<<<512, 256, 0, stream>>>(tgt, emb, xH, xL);

    for (int t = 0; t < T_STEPS; ++t) {
        attn_kernel<<<16, 1024, 0, stream>>>(t, partials, h_raw, lng, lnb, h_curH, h_curL, h_all_b,
                                             whH, whL, keysWk_f, keys_f, av, ctx);
        gates_kernel<<<dim3(16, 2), 256, 0, stream>>>(t, xH, xL, ctx, h_curH, h_curL,
                                                      wihH, wihL, whhH, whhL,
                                                      bih, bhh, c_cur, h_raw, partials);
    }
    finish_kernel<<<16, 512, 0, stream>>>(partials, h_raw, lng, lnb, h_all_b);

    // logits = h_all @ outw^T + out_b  (fp32 out, single-bf16 operands)
    gemm_mfma<<<dim3(16, 79), 256, 0, stream>>>(h_all_b, nullptr, outw_b, nullptr, outb,
                                                out, nullptr, nullptr, 2048, VOCAB, 512);
}